// Round 1
// baseline (64.678 us; speedup 1.0000x reference)
//
#include <hip/hip_runtime.h>

// Problem collapses (see analysis): nn_idx[0] is always 0 because the
// self-distance dist[0,0]=0 is the first minimal element of row 0, so
// neighbor_feat = relu(features[b,0,:]). The N^2 distance matrix is dead code.
//
// Per batch b:
//   f      = relu(features[b])            [N,C]
//   r0     = f[0,:]                       [C]
//   gamma_i = max_j exp(f_ij - r0_j) * (f_ij / max_j f_ij)
//   out_i  = gamma_i / ||gamma||_2

constexpr int kN = 8192;
constexpr int kC = 32;

__global__ __launch_bounds__(256) void gamma_kernel(const float* __restrict__ feats,
                                                    float* __restrict__ out,
                                                    float* __restrict__ sumsq) {
    const int b   = blockIdx.y;
    const int row = blockIdx.x * 256 + threadIdx.x;   // grid.x*256 == kN exactly
    const float* fb = feats + (size_t)b * kN * kC;

    // Load this row's 32 features (8x float4, contiguous) and row 0's.
    const float4* fr = reinterpret_cast<const float4*>(fb + (size_t)row * kC);
    const float4* f0 = reinterpret_cast<const float4*>(fb);

    float v[kC], r0[kC];
#pragma unroll
    for (int q = 0; q < kC / 4; ++q) {
        float4 t = fr[q];
        v[4 * q + 0] = fmaxf(t.x, 0.f);
        v[4 * q + 1] = fmaxf(t.y, 0.f);
        v[4 * q + 2] = fmaxf(t.z, 0.f);
        v[4 * q + 3] = fmaxf(t.w, 0.f);
        float4 z = f0[q];          // block-uniform, L1/L2 resident
        r0[4 * q + 0] = fmaxf(z.x, 0.f);
        r0[4 * q + 1] = fmaxf(z.y, 0.f);
        r0[4 * q + 2] = fmaxf(z.z, 0.f);
        r0[4 * q + 3] = fmaxf(z.w, 0.f);
    }

    // row max of relu'd features (beta denominator)
    float m = 0.f;
#pragma unroll
    for (int j = 0; j < kC; ++j) m = fmaxf(m, v[j]);
    const float inv_m = 1.0f / m;   // m>0 almost surely (all-negative row ~ 2^-32)

    // gamma = max_j exp(v_j - r0_j) * (v_j * inv_m)
    float g = 0.f;
#pragma unroll
    for (int j = 0; j < kC; ++j) {
        g = fmaxf(g, __expf(v[j] - r0[j]) * (v[j] * inv_m));
    }

    out[(size_t)b * kN + row] = g;  // unnormalized; kernel 2 divides by norm

    // sum of squares: wave-level shuffle reduce, one atomic per wave (64 lanes)
    float ss = g * g;
#pragma unroll
    for (int off = 32; off > 0; off >>= 1) ss += __shfl_down(ss, off, 64);
    if ((threadIdx.x & 63) == 0) atomicAdd(&sumsq[b], ss);
}

__global__ __launch_bounds__(256) void norm_kernel(float* __restrict__ out,
                                                   const float* __restrict__ sumsq) {
    const int i = blockIdx.x * 256 + threadIdx.x;   // covers B*kN exactly
    const int b = i >> 13;                          // kN = 8192 = 2^13
    out[i] = out[i] / sqrtf(sumsq[b]);
}

extern "C" void kernel_launch(void* const* d_in, const int* in_sizes, int n_in,
                              void* d_out, int out_size, void* d_ws, size_t ws_size,
                              hipStream_t stream) {
    // inputs: d_in[0]=coords (int32, unused — dead code in reference),
    //         d_in[1]=features (float32 [B,N,C]), d_in[2]=len_batch (unused)
    const float* feats = (const float*)d_in[1];
    float* out = (float*)d_out;
    float* sumsq = (float*)d_ws;

    const int B = out_size / kN;   // 2

    // d_ws is re-poisoned 0xAA before every call — zero the accumulators.
    hipMemsetAsync(sumsq, 0, (size_t)B * sizeof(float), stream);

    dim3 grid1(kN / 256, B);
    gamma_kernel<<<grid1, 256, 0, stream>>>(feats, out, sumsq);

    const int total = B * kN;
    norm_kernel<<<total / 256, 256, 0, stream>>>(out, sumsq);
}